// Round 21
// baseline (88.752 us; speedup 1.0000x reference)
//
#include <hip/hip_runtime.h>
#include <hip/hip_bf16.h>

typedef __attribute__((ext_vector_type(4))) float f32x4;
typedef __attribute__((ext_vector_type(8))) int i32x8;
typedef __attribute__((ext_vector_type(2))) unsigned uintx2;
typedef const __attribute__((address_space(1))) void gvoid_t;
typedef __attribute__((address_space(3))) void lvoid_t;

#define ANGLE_COS 0.8775825618903728f  // cos(0.5)
#define ANGLE_SIN 0.4794255386042030f  // sin(0.5)
#define LOG2E 1.4426950408889634f
#define SCALE1 0x7F7F7F7Fu             // e8m0 exponent 127 = 2^0 in all bytes

static __device__ __forceinline__ float exp2_hw(float x) {
  return __builtin_amdgcn_exp2f(x);  // v_exp_f32: D = 2^S0
}

// pack 4 floats -> 4 OCP e4m3 bytes
static __device__ __forceinline__ unsigned pack4_fp8(float a, float b, float c, float d) {
  int v = __builtin_amdgcn_cvt_pk_fp8_f32(a, b, 0, false);   // bytes 0,1
  v = __builtin_amdgcn_cvt_pk_fp8_f32(c, d, v, true);        // bytes 2,3
  return (unsigned)v;
}

// ---- colprep, split-column: 256 threads = 128 columns x 2 d-halves.
// col[64] regs (~85 VGPR vs 160 for col[128] -> ~2x waves/SIMD, BW-bound).
// Norm = own-half sumsq + LDS exchange with partner half. Single pass over w.
// Output: colinv + fp8 w_norm*log2e granules: granule (q,c) = 8B of
// d = q*8..q*8+7 at wbn + (q*CT + c)*8.
__global__ __launch_bounds__(256) void colprep_kernel(
    const float* __restrict__ w, float* __restrict__ colinv,
    unsigned char* __restrict__ wbn, int C, int CT) {
  __shared__ float sq[256];
  const int tid = threadIdx.x;
  const int cl = tid & 127;            // column within block
  const int h = tid >> 7;              // d-half (0: d<64, 1: d>=64)
  const int c = blockIdx.x * 128 + cl;
  const bool ok = (c < C) && (c < CT);

  float col[64];
  float ss = 0.f;
  const float* wc = w + (size_t)(h * 64) * C + c;
  #pragma unroll 16
  for (int j = 0; j < 64; ++j) {
    float v = ok ? wc[(size_t)j * C] : 0.f;
    col[j] = v;
    ss += v * v;
  }
  sq[cl * 2 + h] = ss;
  __syncthreads();
  const float stot = sq[cl * 2] + sq[cl * 2 + 1];
  const float inv = ok ? (1.0f / sqrtf(stot)) : 0.f;
  if (h == 0 && c < CT) colinv[c] = inv;
  const float invl = inv * LOG2E;  // 0 for pad columns -> zero granules

  if (c < CT) {
    #pragma unroll
    for (int qq = 0; qq < 8; ++qq) {
      const int q = h * 8 + qq;
      uintx2 g;
      g.x = pack4_fp8(col[qq * 8 + 0] * invl, col[qq * 8 + 1] * invl,
                      col[qq * 8 + 2] * invl, col[qq * 8 + 3] * invl);
      g.y = pack4_fp8(col[qq * 8 + 4] * invl, col[qq * 8 + 5] * invl,
                      col[qq * 8 + 6] * invl, col[qq * 8 + 7] * invl);
      *(uintx2*)(wbn + ((size_t)q * CT + c) * 8) = g;
    }
  }
}

// ---- fused: row-normalize -> fp8 Fn, fp32 target-column dot -> ct/cp,
// and rowsum zero-init (runs after colprep; reads colinv).
__global__ void fnorm_tgtdot_kernel(const float* __restrict__ f, const float* __restrict__ w,
                                    const int* __restrict__ target,
                                    const float* __restrict__ colinv,
                                    unsigned char* __restrict__ Fn,
                                    float* __restrict__ ctv, float* __restrict__ cpv,
                                    float* __restrict__ rowsum, int C) {
  const int wave = threadIdx.x >> 6, lane = threadIdx.x & 63;
  const int row = blockIdx.x * 4 + wave;
  const int t = target[row];
  const float* fr = f + (size_t)row * 128;
  float x0 = fr[2 * lane], x1 = fr[2 * lane + 1];
  float wt0 = w[(size_t)(2 * lane) * C + t], wt1 = w[(size_t)(2 * lane + 1) * C + t];
  float sn = x0 * x0 + x1 * x1;
  float sd = x0 * wt0 + x1 * wt1;
  #pragma unroll
  for (int m = 32; m; m >>= 1) {
    sn += __shfl_xor(sn, m);
    sd += __shfl_xor(sd, m);
  }
  const float inv = 1.0f / sqrtf(sn);   // all lanes have sn, sd
  unsigned p = (unsigned)__builtin_amdgcn_cvt_pk_fp8_f32(x0 * inv, x1 * inv, 0, false);
  *(unsigned short*)(Fn + (size_t)row * 128 + lane * 2) = (unsigned short)(p & 0xFFFFu);
  if (lane == 0) {
    float ct = sd * inv * colinv[t];
    ct = fminf(1.f, fmaxf(-1.f, ct));
    float st = sqrtf(fmaxf(0.f, 1.f - ct * ct));
    ctv[row] = ct;
    cpv[row] = ct * ANGLE_COS - st * ANGLE_SIN;
    rowsum[row] = 0.f;
  }
}

// ---- main: 512 thr / 8 waves, rf=4 (64 rows/wave -> 512-row block), 128-col
// fp8 tile, grid (782,4); MX-scaled 16x16x128 MFMA, unit scales. Byte-
// identical to R19 (stable plateau 40.6us: VALU 19.2us, MFMA 9.7, LDS ~7.7).
__global__ __launch_bounds__(512) void arc_main_kernel(
    const unsigned char* __restrict__ wbn, const unsigned char* __restrict__ Fn,
    float* __restrict__ out_part, int CT, int nrows) {
  __shared__ __align__(16) char smem[20480];  // 16KB tile; 20KB 2-pass reduce
  char* Bt = smem;
  float* Rs = (float*)smem;  // reduce scratch, reused after barrier
  const int tid = threadIdx.x;

  const int nx = gridDim.x;
  const int i = blockIdx.x + nx * blockIdx.y;   // hw linear id (x fastest)
  const int v = (i & 7) * (nx >> 1) + (i >> 3); // XCD-contiguous virtual id
  const int vx = v >> 2;                        // col-tile
  const int vy = v & 3;                         // row-group
  const int cbase = vx << 7;

  const int wave = tid >> 6;
  const int lane = tid & 63;
  const int l15 = lane & 15;
  const int lhi = lane >> 4;
  const int ry = nrows >> 2;               // rows per row-group (512)
  const int rowbase = vy * ry + wave * 64; // 64 rows per wave

  // 16 KB tile: wave handles q = wave, wave+8; each q-chunk is 1 KB
  // contiguous in wbn. dest = uniform base + lane*16 (required form).
  #pragma unroll
  for (int k = 0; k < 2; ++k) {
    const int q = wave + k * 8;
    __builtin_amdgcn_global_load_lds(
        (gvoid_t*)(const void*)(wbn + ((size_t)q * CT + cbase) * 8 + lane * 16),
        (lvoid_t*)(void*)(Bt + q * 1024 + lane * 16), 16, 0, 0);
  }

  // A fragments (fp8, K=128: 32B per rf = i32x8) issued BEFORE the barrier.
  i32x8 a[4];
  {
    const char* base = (const char*)Fn + (size_t)(rowbase + l15) * 128 + lhi * 32;
    #pragma unroll
    for (int rf = 0; rf < 4; ++rf)
      a[rf] = *(const i32x8*)(base + rf * 16 * 128);
  }
  __syncthreads();

  float psum[4][4];
  #pragma unroll
  for (int rf = 0; rf < 4; ++rf)
    #pragma unroll
    for (int r = 0; r < 4; ++r) psum[rf][r] = 0.f;

  #pragma unroll
  for (int cf = 0; cf < 8; ++cf) {
    const char* bcol = Bt + (cf * 16 + l15) * 8;
    union { long l[4]; i32x8 v; } bu;
    bu.l[0] = *(const long*)(bcol + (4 * lhi + 0) * 1024);
    bu.l[1] = *(const long*)(bcol + (4 * lhi + 1) * 1024);
    bu.l[2] = *(const long*)(bcol + (4 * lhi + 2) * 1024);
    bu.l[3] = *(const long*)(bcol + (4 * lhi + 3) * 1024);
    __builtin_amdgcn_s_setprio(1);
    f32x4 acc0 = __builtin_amdgcn_mfma_scale_f32_16x16x128_f8f6f4(
        a[0], bu.v, (f32x4){0.f, 0.f, 0.f, 0.f}, 0, 0, 0, SCALE1, 0, SCALE1);
    f32x4 acc1 = __builtin_amdgcn_mfma_scale_f32_16x16x128_f8f6f4(
        a[1], bu.v, (f32x4){0.f, 0.f, 0.f, 0.f}, 0, 0, 0, SCALE1, 0, SCALE1);
    f32x4 acc2 = __builtin_amdgcn_mfma_scale_f32_16x16x128_f8f6f4(
        a[2], bu.v, (f32x4){0.f, 0.f, 0.f, 0.f}, 0, 0, 0, SCALE1, 0, SCALE1);
    f32x4 acc3 = __builtin_amdgcn_mfma_scale_f32_16x16x128_f8f6f4(
        a[3], bu.v, (f32x4){0.f, 0.f, 0.f, 0.f}, 0, 0, 0, SCALE1, 0, SCALE1);
    __builtin_amdgcn_s_setprio(0);
    // D layout (16x16 shape-determined): col = lane&15, row = lhi*4 + r.
    // wbn pre-scaled by log2e -> exp(cos) == 2^acc, single v_exp_f32.
    #pragma unroll
    for (int r = 0; r < 4; ++r) {
      psum[0][r] += exp2_hw(acc0[r]);
      psum[1][r] += exp2_hw(acc1[r]);
      psum[2][r] += exp2_hw(acc2[r]);
      psum[3][r] += exp2_hw(acc3[r]);
    }
  }

  // ---- tail: 2-pass block reduce, scratch [256 rows][stride 20] = 20480 B.
  __syncthreads();  // all waves done reading Bt
  #pragma unroll
  for (int half = 0; half < 2; ++half) {
    if ((wave >> 2) == half) {
      #pragma unroll
      for (int rf = 0; rf < 4; ++rf)
        #pragma unroll
        for (int r = 0; r < 4; ++r) {
          const int rowlocal = (wave & 3) * 64 + rf * 16 + lhi * 4 + r;
          Rs[rowlocal * 20 + l15] = psum[rf][r];
        }
    }
    __syncthreads();
    if (tid < 256) {
      float s = 0.f;
      #pragma unroll
      for (int j = 0; j < 4; ++j) {
        f32x4 vv = *(const f32x4*)&Rs[tid * 20 + j * 4];
        s += vv[0] + vv[1] + vv[2] + vv[3];
      }
      const int row = vy * ry + half * 256 + tid;
      out_part[(size_t)vx * nrows + row] = s;
    }
    __syncthreads();
  }
}

// ---- combine partials: (nrows/256) row-blocks x 16 part-slices ----
__global__ void reduce_kernel(const float* __restrict__ partial, float* __restrict__ rowsum,
                              int nparts, int nrows) {
  const int nrb = nrows >> 8;
  const int row = (blockIdx.x % nrb) * 256 + threadIdx.x;
  const int slice = blockIdx.x / nrb;
  const int pper = (nparts + 15) / 16;
  const int p0 = slice * pper;
  const int p1 = min(nparts, p0 + pper);
  float s = 0.f;
  #pragma unroll 4
  for (int p = p0; p < p1; ++p) s += partial[(size_t)p * nrows + row];
  atomicAdd(&rowsum[row], s);
}

// ---- finalize: loss = mean( log(down_i) - cosplus_i ) ----
__global__ void finalize_kernel(const float* __restrict__ rowsum, const float* __restrict__ ctv,
                                const float* __restrict__ cpv, float* __restrict__ out,
                                int N, float pad, float invN) {
  const int tid = threadIdx.x;
  float local = 0.f;
  for (int i = tid; i < N; i += 256) {
    float top = __expf(cpv[i]);
    float down = rowsum[i] - pad - __expf(ctv[i]) + top;
    local += __logf(down) - cpv[i];
  }
  #pragma unroll
  for (int m = 32; m; m >>= 1) local += __shfl_xor(local, m);
  __shared__ float red[4];
  if ((tid & 63) == 0) red[tid >> 6] = local;
  __syncthreads();
  if (tid == 0) out[0] = (red[0] + red[1] + red[2] + red[3]) * invN;
}

extern "C" void kernel_launch(void* const* d_in, const int* in_sizes, int n_in,
                              void* d_out, int out_size, void* d_ws, size_t ws_size,
                              hipStream_t stream) {
  const float* features = (const float*)d_in[0];
  const int* target = (const int*)d_in[1];
  const float* w = (const float*)d_in[2];
  float* out = (float*)d_out;

  const int N = in_sizes[1];          // 2048
  const int D = in_sizes[0] / N;      // 128 (layout hardcoded in kernels)
  const int C = in_sizes[2] / D;      // 100000
  (void)D;
  const int nct = (C + 127) / 128;    // 782 col tiles
  const int CT = nct * 128;           // padded col count

  char* ws = (char*)d_ws;
  size_t off = 0;
  unsigned char* Fn = (unsigned char*)(ws + off); off += (size_t)N * 128;
  off = (off + 255) & ~(size_t)255;
  float* colinv = (float*)(ws + off); off += (size_t)CT * 4;
  float* rowsum = (float*)(ws + off); off += (size_t)N * 4;
  float* ctv    = (float*)(ws + off); off += (size_t)N * 4;
  float* cpv    = (float*)(ws + off); off += (size_t)N * 4; off = (off + 255) & ~(size_t)255;
  float* partial = (float*)(ws + off);
  const size_t need_store = off + (size_t)nct * N * 4;
  const size_t wbn_off = (need_store + 255) & ~(size_t)255;
  unsigned char* wbn = (unsigned char*)(ws + wbn_off);

  colprep_kernel<<<nct, 256, 0, stream>>>(w, colinv, wbn, C, CT);
  fnorm_tgtdot_kernel<<<N / 4, 256, 0, stream>>>(features, w, target, colinv, Fn, ctv, cpv,
                                                 rowsum, C);

  dim3 grid(nct, 4);
  arc_main_kernel<<<grid, 512, 0, stream>>>(wbn, Fn, partial, CT, N);
  reduce_kernel<<<(N / 256) * 16, 256, 0, stream>>>(partial, rowsum, nct, N);
  finalize_kernel<<<1, 256, 0, stream>>>(rowsum, ctv, cpv, out, N,
                                         (float)(CT - C), 1.0f / (float)N);
}

// Round 22
// 67.316 us; speedup vs baseline: 1.3184x; 1.3184x over previous
//
#include <hip/hip_runtime.h>
#include <hip/hip_bf16.h>

typedef __attribute__((ext_vector_type(4))) float f32x4;
typedef __attribute__((ext_vector_type(8))) int i32x8;
typedef __attribute__((ext_vector_type(2))) unsigned uintx2;
typedef const __attribute__((address_space(1))) void gvoid_t;
typedef __attribute__((address_space(3))) void lvoid_t;

#define ANGLE_COS 0.8775825618903728f  // cos(0.5)
#define ANGLE_SIN 0.4794255386042030f  // sin(0.5)
#define LOG2E 1.4426950408889634f
#define SCALE1 0x7F7F7F7Fu             // e8m0 exponent 127 = 2^0 in all bytes

static __device__ __forceinline__ float exp2_hw(float x) {
  return __builtin_amdgcn_exp2f(x);  // v_exp_f32: D = 2^S0
}

// pack 4 floats -> 4 OCP e4m3 bytes
static __device__ __forceinline__ unsigned pack4_fp8(float a, float b, float c, float d) {
  int v = __builtin_amdgcn_cvt_pk_fp8_f32(a, b, 0, false);   // bytes 0,1
  v = __builtin_amdgcn_cvt_pk_fp8_f32(c, d, v, true);        // bytes 2,3
  return (unsigned)v;
}

// ---- colprep, split-column: 256 threads = 128 columns x 2 d-halves.
// col[64] FULLY UNROLLED (R21 bug: "#pragma unroll 16" left runtime indices
// -> rule-#20 scratch spill, VGPR 36, 55-75us). Full unroll -> static
// indices -> registers (~85 VGPR, ~6 waves/SIMD, BW-bound).
// Norm = own-half sumsq + LDS exchange. Single pass over w.
// Output: colinv + fp8 w_norm*log2e granules: granule (q,c) = 8B of
// d = q*8..q*8+7 at wbn + (q*CT + c)*8.
__global__ __launch_bounds__(256) void colprep_kernel(
    const float* __restrict__ w, float* __restrict__ colinv,
    unsigned char* __restrict__ wbn, int C, int CT) {
  __shared__ float sq[256];
  const int tid = threadIdx.x;
  const int cl = tid & 127;            // column within block
  const int h = tid >> 7;              // d-half (0: d<64, 1: d>=64)
  const int c = blockIdx.x * 128 + cl;
  const bool ok = (c < C);

  float col[64];
  float ss = 0.f;
  const float* wc = w + (size_t)(h * 64) * C + c;
  #pragma unroll
  for (int j = 0; j < 64; ++j) {
    float v = ok ? wc[(size_t)j * C] : 0.f;
    col[j] = v;
    ss += v * v;
  }
  sq[cl * 2 + h] = ss;
  __syncthreads();
  const float stot = sq[cl * 2] + sq[cl * 2 + 1];
  const float inv = ok ? (1.0f / sqrtf(stot)) : 0.f;
  if (h == 0) colinv[c] = inv;
  const float invl = inv * LOG2E;  // 0 for pad columns -> zero granules

  #pragma unroll
  for (int qq = 0; qq < 8; ++qq) {
    const int q = h * 8 + qq;
    uintx2 g;
    g.x = pack4_fp8(col[qq * 8 + 0] * invl, col[qq * 8 + 1] * invl,
                    col[qq * 8 + 2] * invl, col[qq * 8 + 3] * invl);
    g.y = pack4_fp8(col[qq * 8 + 4] * invl, col[qq * 8 + 5] * invl,
                    col[qq * 8 + 6] * invl, col[qq * 8 + 7] * invl);
    *(uintx2*)(wbn + ((size_t)q * CT + c) * 8) = g;
  }
}

// ---- fused: row-normalize -> fp8 Fn, fp32 target-column dot -> ct/cp,
// and rowsum zero-init (runs after colprep; reads colinv).
__global__ void fnorm_tgtdot_kernel(const float* __restrict__ f, const float* __restrict__ w,
                                    const int* __restrict__ target,
                                    const float* __restrict__ colinv,
                                    unsigned char* __restrict__ Fn,
                                    float* __restrict__ ctv, float* __restrict__ cpv,
                                    float* __restrict__ rowsum, int C) {
  const int wave = threadIdx.x >> 6, lane = threadIdx.x & 63;
  const int row = blockIdx.x * 4 + wave;
  const int t = target[row];
  const float* fr = f + (size_t)row * 128;
  float x0 = fr[2 * lane], x1 = fr[2 * lane + 1];
  float wt0 = w[(size_t)(2 * lane) * C + t], wt1 = w[(size_t)(2 * lane + 1) * C + t];
  float sn = x0 * x0 + x1 * x1;
  float sd = x0 * wt0 + x1 * wt1;
  #pragma unroll
  for (int m = 32; m; m >>= 1) {
    sn += __shfl_xor(sn, m);
    sd += __shfl_xor(sd, m);
  }
  const float inv = 1.0f / sqrtf(sn);   // all lanes have sn, sd
  unsigned p = (unsigned)__builtin_amdgcn_cvt_pk_fp8_f32(x0 * inv, x1 * inv, 0, false);
  *(unsigned short*)(Fn + (size_t)row * 128 + lane * 2) = (unsigned short)(p & 0xFFFFu);
  if (lane == 0) {
    float ct = sd * inv * colinv[t];
    ct = fminf(1.f, fmaxf(-1.f, ct));
    float st = sqrtf(fmaxf(0.f, 1.f - ct * ct));
    ctv[row] = ct;
    cpv[row] = ct * ANGLE_COS - st * ANGLE_SIN;
    rowsum[row] = 0.f;
  }
}

// ---- main: 512 thr / 8 waves, rf=4 (64 rows/wave -> 512-row block), 128-col
// fp8 tile, grid (782,4); MX-scaled 16x16x128 MFMA, unit scales. Byte-
// identical to R19 (stable plateau 40.6us: VALU 19.2us, MFMA 9.7, LDS ~7.7).
__global__ __launch_bounds__(512) void arc_main_kernel(
    const unsigned char* __restrict__ wbn, const unsigned char* __restrict__ Fn,
    float* __restrict__ out_part, int CT, int nrows) {
  __shared__ __align__(16) char smem[20480];  // 16KB tile; 20KB 2-pass reduce
  char* Bt = smem;
  float* Rs = (float*)smem;  // reduce scratch, reused after barrier
  const int tid = threadIdx.x;

  const int nx = gridDim.x;
  const int i = blockIdx.x + nx * blockIdx.y;   // hw linear id (x fastest)
  const int v = (i & 7) * (nx >> 1) + (i >> 3); // XCD-contiguous virtual id
  const int vx = v >> 2;                        // col-tile
  const int vy = v & 3;                         // row-group
  const int cbase = vx << 7;

  const int wave = tid >> 6;
  const int lane = tid & 63;
  const int l15 = lane & 15;
  const int lhi = lane >> 4;
  const int ry = nrows >> 2;               // rows per row-group (512)
  const int rowbase = vy * ry + wave * 64; // 64 rows per wave

  // 16 KB tile: wave handles q = wave, wave+8; each q-chunk is 1 KB
  // contiguous in wbn. dest = uniform base + lane*16 (required form).
  #pragma unroll
  for (int k = 0; k < 2; ++k) {
    const int q = wave + k * 8;
    __builtin_amdgcn_global_load_lds(
        (gvoid_t*)(const void*)(wbn + ((size_t)q * CT + cbase) * 8 + lane * 16),
        (lvoid_t*)(void*)(Bt + q * 1024 + lane * 16), 16, 0, 0);
  }

  // A fragments (fp8, K=128: 32B per rf = i32x8) issued BEFORE the barrier.
  i32x8 a[4];
  {
    const char* base = (const char*)Fn + (size_t)(rowbase + l15) * 128 + lhi * 32;
    #pragma unroll
    for (int rf = 0; rf < 4; ++rf)
      a[rf] = *(const i32x8*)(base + rf * 16 * 128);
  }
  __syncthreads();

  float psum[4][4];
  #pragma unroll
  for (int rf = 0; rf < 4; ++rf)
    #pragma unroll
    for (int r = 0; r < 4; ++r) psum[rf][r] = 0.f;

  #pragma unroll
  for (int cf = 0; cf < 8; ++cf) {
    const char* bcol = Bt + (cf * 16 + l15) * 8;
    union { long l[4]; i32x8 v; } bu;
    bu.l[0] = *(const long*)(bcol + (4 * lhi + 0) * 1024);
    bu.l[1] = *(const long*)(bcol + (4 * lhi + 1) * 1024);
    bu.l[2] = *(const long*)(bcol + (4 * lhi + 2) * 1024);
    bu.l[3] = *(const long*)(bcol + (4 * lhi + 3) * 1024);
    __builtin_amdgcn_s_setprio(1);
    f32x4 acc0 = __builtin_amdgcn_mfma_scale_f32_16x16x128_f8f6f4(
        a[0], bu.v, (f32x4){0.f, 0.f, 0.f, 0.f}, 0, 0, 0, SCALE1, 0, SCALE1);
    f32x4 acc1 = __builtin_amdgcn_mfma_scale_f32_16x16x128_f8f6f4(
        a[1], bu.v, (f32x4){0.f, 0.f, 0.f, 0.f}, 0, 0, 0, SCALE1, 0, SCALE1);
    f32x4 acc2 = __builtin_amdgcn_mfma_scale_f32_16x16x128_f8f6f4(
        a[2], bu.v, (f32x4){0.f, 0.f, 0.f, 0.f}, 0, 0, 0, SCALE1, 0, SCALE1);
    f32x4 acc3 = __builtin_amdgcn_mfma_scale_f32_16x16x128_f8f6f4(
        a[3], bu.v, (f32x4){0.f, 0.f, 0.f, 0.f}, 0, 0, 0, SCALE1, 0, SCALE1);
    __builtin_amdgcn_s_setprio(0);
    // D layout (16x16 shape-determined): col = lane&15, row = lhi*4 + r.
    // wbn pre-scaled by log2e -> exp(cos) == 2^acc, single v_exp_f32.
    #pragma unroll
    for (int r = 0; r < 4; ++r) {
      psum[0][r] += exp2_hw(acc0[r]);
      psum[1][r] += exp2_hw(acc1[r]);
      psum[2][r] += exp2_hw(acc2[r]);
      psum[3][r] += exp2_hw(acc3[r]);
    }
  }

  // ---- tail: 2-pass block reduce, scratch [256 rows][stride 20] = 20480 B.
  __syncthreads();  // all waves done reading Bt
  #pragma unroll
  for (int half = 0; half < 2; ++half) {
    if ((wave >> 2) == half) {
      #pragma unroll
      for (int rf = 0; rf < 4; ++rf)
        #pragma unroll
        for (int r = 0; r < 4; ++r) {
          const int rowlocal = (wave & 3) * 64 + rf * 16 + lhi * 4 + r;
          Rs[rowlocal * 20 + l15] = psum[rf][r];
        }
    }
    __syncthreads();
    if (tid < 256) {
      float s = 0.f;
      #pragma unroll
      for (int j = 0; j < 4; ++j) {
        f32x4 vv = *(const f32x4*)&Rs[tid * 20 + j * 4];
        s += vv[0] + vv[1] + vv[2] + vv[3];
      }
      const int row = vy * ry + half * 256 + tid;
      out_part[(size_t)vx * nrows + row] = s;
    }
    __syncthreads();
  }
}

// ---- combine partials: (nrows/256) row-blocks x 16 part-slices ----
__global__ void reduce_kernel(const float* __restrict__ partial, float* __restrict__ rowsum,
                              int nparts, int nrows) {
  const int nrb = nrows >> 8;
  const int row = (blockIdx.x % nrb) * 256 + threadIdx.x;
  const int slice = blockIdx.x / nrb;
  const int pper = (nparts + 15) / 16;
  const int p0 = slice * pper;
  const int p1 = min(nparts, p0 + pper);
  float s = 0.f;
  #pragma unroll 4
  for (int p = p0; p < p1; ++p) s += partial[(size_t)p * nrows + row];
  atomicAdd(&rowsum[row], s);
}

// ---- finalize: loss = mean( log(down_i) - cosplus_i ) ----
__global__ void finalize_kernel(const float* __restrict__ rowsum, const float* __restrict__ ctv,
                                const float* __restrict__ cpv, float* __restrict__ out,
                                int N, float pad, float invN) {
  const int tid = threadIdx.x;
  float local = 0.f;
  for (int i = tid; i < N; i += 256) {
    float top = __expf(cpv[i]);
    float down = rowsum[i] - pad - __expf(ctv[i]) + top;
    local += __logf(down) - cpv[i];
  }
  #pragma unroll
  for (int m = 32; m; m >>= 1) local += __shfl_xor(local, m);
  __shared__ float red[4];
  if ((tid & 63) == 0) red[tid >> 6] = local;
  __syncthreads();
  if (tid == 0) out[0] = (red[0] + red[1] + red[2] + red[3]) * invN;
}

extern "C" void kernel_launch(void* const* d_in, const int* in_sizes, int n_in,
                              void* d_out, int out_size, void* d_ws, size_t ws_size,
                              hipStream_t stream) {
  const float* features = (const float*)d_in[0];
  const int* target = (const int*)d_in[1];
  const float* w = (const float*)d_in[2];
  float* out = (float*)d_out;

  const int N = in_sizes[1];          // 2048
  const int D = in_sizes[0] / N;      // 128 (layout hardcoded in kernels)
  const int C = in_sizes[2] / D;      // 100000
  (void)D;
  const int nct = (C + 127) / 128;    // 782 col tiles
  const int CT = nct * 128;           // padded col count

  char* ws = (char*)d_ws;
  size_t off = 0;
  unsigned char* Fn = (unsigned char*)(ws + off); off += (size_t)N * 128;
  off = (off + 255) & ~(size_t)255;
  float* colinv = (float*)(ws + off); off += (size_t)CT * 4;
  float* rowsum = (float*)(ws + off); off += (size_t)N * 4;
  float* ctv    = (float*)(ws + off); off += (size_t)N * 4;
  float* cpv    = (float*)(ws + off); off += (size_t)N * 4; off = (off + 255) & ~(size_t)255;
  float* partial = (float*)(ws + off);
  const size_t need_store = off + (size_t)nct * N * 4;
  const size_t wbn_off = (need_store + 255) & ~(size_t)255;
  unsigned char* wbn = (unsigned char*)(ws + wbn_off);

  colprep_kernel<<<nct, 256, 0, stream>>>(w, colinv, wbn, C, CT);
  fnorm_tgtdot_kernel<<<N / 4, 256, 0, stream>>>(features, w, target, colinv, Fn, ctv, cpv,
                                                 rowsum, C);

  dim3 grid(nct, 4);
  arc_main_kernel<<<grid, 512, 0, stream>>>(wbn, Fn, partial, CT, N);
  reduce_kernel<<<(N / 256) * 16, 256, 0, stream>>>(partial, rowsum, nct, N);
  finalize_kernel<<<1, 256, 0, stream>>>(rowsum, ctv, cpv, out, N,
                                         (float)(CT - C), 1.0f / (float)N);
}

// Round 23
// 67.242 us; speedup vs baseline: 1.3199x; 1.0011x over previous
//
#include <hip/hip_runtime.h>
#include <hip/hip_bf16.h>

typedef __attribute__((ext_vector_type(4))) float f32x4;
typedef __attribute__((ext_vector_type(8))) int i32x8;
typedef __attribute__((ext_vector_type(2))) unsigned uintx2;
typedef const __attribute__((address_space(1))) void gvoid_t;
typedef __attribute__((address_space(3))) void lvoid_t;

#define ANGLE_COS 0.8775825618903728f  // cos(0.5)
#define ANGLE_SIN 0.4794255386042030f  // sin(0.5)
#define LOG2E 1.4426950408889634f
#define SCALE1 0x7F7F7F7Fu             // e8m0 exponent 127 = 2^0 in all bytes

static __device__ __forceinline__ float exp2_hw(float x) {
  return __builtin_amdgcn_exp2f(x);  // v_exp_f32: D = 2^S0
}

// pack 4 floats -> 4 OCP e4m3 bytes
static __device__ __forceinline__ unsigned pack4_fp8(float a, float b, float c, float d) {
  int v = __builtin_amdgcn_cvt_pk_fp8_f32(a, b, 0, false);   // bytes 0,1
  v = __builtin_amdgcn_cvt_pk_fp8_f32(c, d, v, true);        // bytes 2,3
  return (unsigned)v;
}

// ---- fused prep: blocks [0, nct) = split-column colprep (R22's proven
// full-unroll form); blocks [nct, nct+N/4) = fnorm + RAW tgtdot (sd*inv;
// colinv[t] folded in finalize -> no ordering dependency between block types).
__global__ __launch_bounds__(256) void prep_kernel(
    const float* __restrict__ w, const float* __restrict__ f,
    const int* __restrict__ target, float* __restrict__ colinv,
    unsigned char* __restrict__ wbn, unsigned char* __restrict__ Fn,
    float* __restrict__ ctv, float* __restrict__ rowsum,
    int C, int CT, int nct) {
  const int bx = blockIdx.x;
  if (bx < nct) {
    // -------- colprep: 256 threads = 128 columns x 2 d-halves --------
    // col[64] fully unrolled -> registers (R21 lesson: partial unroll ->
    // rule-#20 scratch spill). Norm via LDS exchange of half sums.
    __shared__ float sq[256];
    const int tid = threadIdx.x;
    const int cl = tid & 127;            // column within block
    const int h = tid >> 7;              // d-half (0: d<64, 1: d>=64)
    const int c = bx * 128 + cl;
    const bool ok = (c < C);

    float col[64];
    float ss = 0.f;
    const float* wc = w + (size_t)(h * 64) * C + c;
    #pragma unroll
    for (int j = 0; j < 64; ++j) {
      float v = ok ? wc[(size_t)j * C] : 0.f;
      col[j] = v;
      ss += v * v;
    }
    sq[cl * 2 + h] = ss;
    __syncthreads();
    const float stot = sq[cl * 2] + sq[cl * 2 + 1];
    const float inv = ok ? (1.0f / sqrtf(stot)) : 0.f;
    if (h == 0) colinv[c] = inv;
    const float invl = inv * LOG2E;  // 0 for pad columns -> zero granules

    #pragma unroll
    for (int qq = 0; qq < 8; ++qq) {
      const int q = h * 8 + qq;
      uintx2 g;
      g.x = pack4_fp8(col[qq * 8 + 0] * invl, col[qq * 8 + 1] * invl,
                      col[qq * 8 + 2] * invl, col[qq * 8 + 3] * invl);
      g.y = pack4_fp8(col[qq * 8 + 4] * invl, col[qq * 8 + 5] * invl,
                      col[qq * 8 + 6] * invl, col[qq * 8 + 7] * invl);
      *(uintx2*)(wbn + ((size_t)q * CT + c) * 8) = g;
    }
  } else {
    // -------- fnorm + raw tgtdot + rowsum zero-init --------
    const int wave = threadIdx.x >> 6, lane = threadIdx.x & 63;
    const int row = (bx - nct) * 4 + wave;
    const int t = target[row];
    const float* fr = f + (size_t)row * 128;
    float x0 = fr[2 * lane], x1 = fr[2 * lane + 1];
    float wt0 = w[(size_t)(2 * lane) * C + t], wt1 = w[(size_t)(2 * lane + 1) * C + t];
    float sn = x0 * x0 + x1 * x1;
    float sd = x0 * wt0 + x1 * wt1;
    #pragma unroll
    for (int m = 32; m; m >>= 1) {
      sn += __shfl_xor(sn, m);
      sd += __shfl_xor(sd, m);
    }
    const float inv = 1.0f / sqrtf(sn);   // all lanes have sn, sd
    unsigned p = (unsigned)__builtin_amdgcn_cvt_pk_fp8_f32(x0 * inv, x1 * inv, 0, false);
    *(unsigned short*)(Fn + (size_t)row * 128 + lane * 2) = (unsigned short)(p & 0xFFFFu);
    if (lane == 0) {
      ctv[row] = sd * inv;   // raw dot / ||f||; colinv[t] folded in finalize
      rowsum[row] = 0.f;
    }
  }
}

// ---- main: 512 thr / 8 waves, rf=4 (64 rows/wave -> 512-row block), 128-col
// fp8 tile, grid (782,4); MX-scaled 16x16x128 MFMA, unit scales. Byte-
// identical to R19/R22 (stable plateau 40.6us).
__global__ __launch_bounds__(512) void arc_main_kernel(
    const unsigned char* __restrict__ wbn, const unsigned char* __restrict__ Fn,
    float* __restrict__ out_part, int CT, int nrows) {
  __shared__ __align__(16) char smem[20480];  // 16KB tile; 20KB 2-pass reduce
  char* Bt = smem;
  float* Rs = (float*)smem;  // reduce scratch, reused after barrier
  const int tid = threadIdx.x;

  const int nx = gridDim.x;
  const int i = blockIdx.x + nx * blockIdx.y;   // hw linear id (x fastest)
  const int v = (i & 7) * (nx >> 1) + (i >> 3); // XCD-contiguous virtual id
  const int vx = v >> 2;                        // col-tile
  const int vy = v & 3;                         // row-group
  const int cbase = vx << 7;

  const int wave = tid >> 6;
  const int lane = tid & 63;
  const int l15 = lane & 15;
  const int lhi = lane >> 4;
  const int ry = nrows >> 2;               // rows per row-group (512)
  const int rowbase = vy * ry + wave * 64; // 64 rows per wave

  // 16 KB tile: wave handles q = wave, wave+8; each q-chunk is 1 KB
  // contiguous in wbn. dest = uniform base + lane*16 (required form).
  #pragma unroll
  for (int k = 0; k < 2; ++k) {
    const int q = wave + k * 8;
    __builtin_amdgcn_global_load_lds(
        (gvoid_t*)(const void*)(wbn + ((size_t)q * CT + cbase) * 8 + lane * 16),
        (lvoid_t*)(void*)(Bt + q * 1024 + lane * 16), 16, 0, 0);
  }

  // A fragments (fp8, K=128: 32B per rf = i32x8) issued BEFORE the barrier.
  i32x8 a[4];
  {
    const char* base = (const char*)Fn + (size_t)(rowbase + l15) * 128 + lhi * 32;
    #pragma unroll
    for (int rf = 0; rf < 4; ++rf)
      a[rf] = *(const i32x8*)(base + rf * 16 * 128);
  }
  __syncthreads();

  float psum[4][4];
  #pragma unroll
  for (int rf = 0; rf < 4; ++rf)
    #pragma unroll
    for (int r = 0; r < 4; ++r) psum[rf][r] = 0.f;

  #pragma unroll
  for (int cf = 0; cf < 8; ++cf) {
    const char* bcol = Bt + (cf * 16 + l15) * 8;
    union { long l[4]; i32x8 v; } bu;
    bu.l[0] = *(const long*)(bcol + (4 * lhi + 0) * 1024);
    bu.l[1] = *(const long*)(bcol + (4 * lhi + 1) * 1024);
    bu.l[2] = *(const long*)(bcol + (4 * lhi + 2) * 1024);
    bu.l[3] = *(const long*)(bcol + (4 * lhi + 3) * 1024);
    __builtin_amdgcn_s_setprio(1);
    f32x4 acc0 = __builtin_amdgcn_mfma_scale_f32_16x16x128_f8f6f4(
        a[0], bu.v, (f32x4){0.f, 0.f, 0.f, 0.f}, 0, 0, 0, SCALE1, 0, SCALE1);
    f32x4 acc1 = __builtin_amdgcn_mfma_scale_f32_16x16x128_f8f6f4(
        a[1], bu.v, (f32x4){0.f, 0.f, 0.f, 0.f}, 0, 0, 0, SCALE1, 0, SCALE1);
    f32x4 acc2 = __builtin_amdgcn_mfma_scale_f32_16x16x128_f8f6f4(
        a[2], bu.v, (f32x4){0.f, 0.f, 0.f, 0.f}, 0, 0, 0, SCALE1, 0, SCALE1);
    f32x4 acc3 = __builtin_amdgcn_mfma_scale_f32_16x16x128_f8f6f4(
        a[3], bu.v, (f32x4){0.f, 0.f, 0.f, 0.f}, 0, 0, 0, SCALE1, 0, SCALE1);
    __builtin_amdgcn_s_setprio(0);
    // D layout (16x16 shape-determined): col = lane&15, row = lhi*4 + r.
    // wbn pre-scaled by log2e -> exp(cos) == 2^acc, single v_exp_f32.
    #pragma unroll
    for (int r = 0; r < 4; ++r) {
      psum[0][r] += exp2_hw(acc0[r]);
      psum[1][r] += exp2_hw(acc1[r]);
      psum[2][r] += exp2_hw(acc2[r]);
      psum[3][r] += exp2_hw(acc3[r]);
    }
  }

  // ---- tail: 2-pass block reduce, scratch [256 rows][stride 20] = 20480 B.
  __syncthreads();  // all waves done reading Bt
  #pragma unroll
  for (int half = 0; half < 2; ++half) {
    if ((wave >> 2) == half) {
      #pragma unroll
      for (int rf = 0; rf < 4; ++rf)
        #pragma unroll
        for (int r = 0; r < 4; ++r) {
          const int rowlocal = (wave & 3) * 64 + rf * 16 + lhi * 4 + r;
          Rs[rowlocal * 20 + l15] = psum[rf][r];
        }
    }
    __syncthreads();
    if (tid < 256) {
      float s = 0.f;
      #pragma unroll
      for (int j = 0; j < 4; ++j) {
        f32x4 vv = *(const f32x4*)&Rs[tid * 20 + j * 4];
        s += vv[0] + vv[1] + vv[2] + vv[3];
      }
      const int row = vy * ry + half * 256 + tid;
      out_part[(size_t)vx * nrows + row] = s;
    }
    __syncthreads();
  }
}

// ---- combine partials: (nrows/256) row-blocks x 16 part-slices ----
__global__ void reduce_kernel(const float* __restrict__ partial, float* __restrict__ rowsum,
                              int nparts, int nrows) {
  const int nrb = nrows >> 8;
  const int row = (blockIdx.x % nrb) * 256 + threadIdx.x;
  const int slice = blockIdx.x / nrb;
  const int pper = (nparts + 15) / 16;
  const int p0 = slice * pper;
  const int p1 = min(nparts, p0 + pper);
  float s = 0.f;
  #pragma unroll 4
  for (int p = p0; p < p1; ++p) s += partial[(size_t)p * nrows + row];
  atomicAdd(&rowsum[row], s);
}

// ---- finalize: ct = raw_dot * colinv[t]; cp = cos(theta+m);
// loss = mean( log(down) - cp ).
__global__ void finalize_kernel(const float* __restrict__ rowsum, const float* __restrict__ ctv,
                                const int* __restrict__ target,
                                const float* __restrict__ colinv, float* __restrict__ out,
                                int N, float pad, float invN) {
  const int tid = threadIdx.x;
  float local = 0.f;
  for (int i = tid; i < N; i += 256) {
    float ct = ctv[i] * colinv[target[i]];
    ct = fminf(1.f, fmaxf(-1.f, ct));
    float st = sqrtf(fmaxf(0.f, 1.f - ct * ct));
    float cp = ct * ANGLE_COS - st * ANGLE_SIN;
    float top = __expf(cp);
    float down = rowsum[i] - pad - __expf(ct) + top;
    local += __logf(down) - cp;
  }
  #pragma unroll
  for (int m = 32; m; m >>= 1) local += __shfl_xor(local, m);
  __shared__ float red[4];
  if ((tid & 63) == 0) red[tid >> 6] = local;
  __syncthreads();
  if (tid == 0) out[0] = (red[0] + red[1] + red[2] + red[3]) * invN;
}

extern "C" void kernel_launch(void* const* d_in, const int* in_sizes, int n_in,
                              void* d_out, int out_size, void* d_ws, size_t ws_size,
                              hipStream_t stream) {
  const float* features = (const float*)d_in[0];
  const int* target = (const int*)d_in[1];
  const float* w = (const float*)d_in[2];
  float* out = (float*)d_out;

  const int N = in_sizes[1];          // 2048
  const int D = in_sizes[0] / N;      // 128 (layout hardcoded in kernels)
  const int C = in_sizes[2] / D;      // 100000
  (void)D;
  const int nct = (C + 127) / 128;    // 782 col tiles
  const int CT = nct * 128;           // padded col count

  char* ws = (char*)d_ws;
  size_t off = 0;
  unsigned char* Fn = (unsigned char*)(ws + off); off += (size_t)N * 128;
  off = (off + 255) & ~(size_t)255;
  float* colinv = (float*)(ws + off); off += (size_t)CT * 4;
  float* rowsum = (float*)(ws + off); off += (size_t)N * 4;
  float* ctv    = (float*)(ws + off); off += (size_t)N * 4; off = (off + 255) & ~(size_t)255;
  float* partial = (float*)(ws + off);
  const size_t need_store = off + (size_t)nct * N * 4;
  const size_t wbn_off = (need_store + 255) & ~(size_t)255;
  unsigned char* wbn = (unsigned char*)(ws + wbn_off);

  prep_kernel<<<nct + N / 4, 256, 0, stream>>>(w, features, target, colinv, wbn, Fn,
                                               ctv, rowsum, C, CT, nct);

  dim3 grid(nct, 4);
  arc_main_kernel<<<grid, 512, 0, stream>>>(wbn, Fn, partial, CT, N);
  reduce_kernel<<<(N / 256) * 16, 256, 0, stream>>>(partial, rowsum, nct, N);
  finalize_kernel<<<1, 256, 0, stream>>>(rowsum, ctv, target, colinv, out, N,
                                         (float)(CT - C), 1.0f / (float)N);
}